// Round 2
// baseline (862.911 us; speedup 1.0000x reference)
//
#include <hip/hip_runtime.h>
#include <hip/hip_bf16.h>

#define B_  16
#define S_  4096
#define D_  512
#define M_  2048
#define ROWS (B_ * S_)   // 65536
#define N3D  (3 * D_)    // 1536

typedef __attribute__((ext_vector_type(8))) short bf16x8;
typedef __attribute__((ext_vector_type(4))) float f32x4;

__device__ __forceinline__ void load16(const void* g, void* l) {
    __builtin_amdgcn_global_load_lds(
        (const __attribute__((address_space(1))) void*)g,
        (__attribute__((address_space(3))) void*)l, 16, 0, 0);
}

// ---------------- conversions ----------------

__global__ __launch_bounds__(256) void cvt_x_kernel(const float* __restrict__ x,
                                                    __hip_bfloat16* __restrict__ xb) {
    long i = (long)blockIdx.x * 256 + threadIdx.x;   // [0, ROWS*D_/8)
    const float4* x4 = (const float4*)x;
    float4 a = x4[2 * i], b = x4[2 * i + 1];
    union { __hip_bfloat16 h[8]; int4 v; } u;
    u.h[0] = __float2bfloat16(a.x); u.h[1] = __float2bfloat16(a.y);
    u.h[2] = __float2bfloat16(a.z); u.h[3] = __float2bfloat16(a.w);
    u.h[4] = __float2bfloat16(b.x); u.h[5] = __float2bfloat16(b.y);
    u.h[6] = __float2bfloat16(b.z); u.h[7] = __float2bfloat16(b.w);
    ((int4*)xb)[i] = u.v;
}

// W_qkv (512 x 1536 row-major fp32) -> Wt (1536 x 512) bf16, LDS tile transpose
__global__ __launch_bounds__(256) void cvt_w_kernel(const float* __restrict__ w,
                                                    __hip_bfloat16* __restrict__ wt) {
    __shared__ float t[64][65];
    int nb = blockIdx.x * 64;   // 24
    int kb = blockIdx.y * 64;   // 8
    int tx = threadIdx.x & 63, ty = threadIdx.x >> 6;
    #pragma unroll
    for (int r = ty; r < 64; r += 4)
        t[r][tx] = w[(long)(kb + r) * N3D + nb + tx];      // coalesced 256B reads
    __syncthreads();
    #pragma unroll
    for (int r = ty; r < 64; r += 4)
        wt[(long)(nb + r) * 512 + kb + tx] = __float2bfloat16(t[tx][r]); // coalesced 128B writes
}

// ---------------- qkv GEMM (m97 structure) ----------------
// C[65536 x 1536] = Xb @ Wt^T + bias; cols 0..511->q(f32), 512..1023->k(f32), 1024..1535->v(bf16)
__global__ __launch_bounds__(256) void gemm_qkv_kernel(
    const __hip_bfloat16* __restrict__ Xb,
    const __hip_bfloat16* __restrict__ Wt,
    const float* __restrict__ bias,
    float* __restrict__ qout, float* __restrict__ kout,
    __hip_bfloat16* __restrict__ vout)
{
    __shared__ __hip_bfloat16 As[128 * 32];   // unpadded: global_load_lds needs lane-contiguous
    __shared__ __hip_bfloat16 Bs[128 * 32];
    const int tid  = threadIdx.x;
    const int n0   = blockIdx.x * 128;        // n fast (12) -> Xb tile L2 reuse across n
    const int m0   = blockIdx.y * 128;
    const int wave = tid >> 6, lane = tid & 63;
    const int wm   = (wave >> 1) * 64, wn = (wave & 1) * 64;
    const int quad = lane >> 4, l16 = lane & 15;

    // staging chunks: c -> row c>>2, kcol (c&3)*8 ; LDS byte offset c*16 (lane-contiguous)
    const int c0 = tid, c1 = tid + 256;
    const int r0 = c0 >> 2, kc0 = (c0 & 3) * 8;
    const int r1 = c1 >> 2, kc1 = (c1 & 3) * 8;

    const __hip_bfloat16* Ab = Xb + (long)m0 * 512;
    const __hip_bfloat16* Bb = Wt + (long)n0 * 512;

    f32x4 acc[4][4] = {};

    for (int k0 = 0; k0 < 512; k0 += 32) {
        __syncthreads();   // WAR: prior frag reads done before overwrite
        load16(Ab + (long)r0 * 512 + k0 + kc0, (char*)As + c0 * 16);
        load16(Ab + (long)r1 * 512 + k0 + kc1, (char*)As + c1 * 16);
        load16(Bb + (long)r0 * 512 + k0 + kc0, (char*)Bs + c0 * 16);
        load16(Bb + (long)r1 * 512 + k0 + kc1, (char*)Bs + c1 * 16);
        __syncthreads();   // drains vmcnt -> LDS valid

        bf16x8 af[4], bf[4];
        #pragma unroll
        for (int t = 0; t < 4; t++) {
            af[t] = *(const bf16x8*)&As[(wm + t * 16 + l16) * 32 + quad * 8];
            bf[t] = *(const bf16x8*)&Bs[(wn + t * 16 + l16) * 32 + quad * 8];
        }
        #pragma unroll
        for (int mt = 0; mt < 4; mt++)
            #pragma unroll
            for (int nt = 0; nt < 4; nt++)
                acc[mt][nt] = __builtin_amdgcn_mfma_f32_16x16x32_bf16(
                    af[mt], bf[nt], acc[mt][nt], 0, 0, 0);
    }

    // ---- epilogue: per-wave LDS transpose -> coalesced 256B stores ----
    __syncthreads();   // all frag reads done; reuse As/Bs as 4x 4KB fp32 regions
    float* ep = ((wave < 2) ? (float*)As : (float*)Bs) + (wave & 1) * 1024;
    const int colblk = n0 + wn;   // 64-aligned => whole wave-block in one of q/k/v

    float bcol[4];
    #pragma unroll
    for (int nt = 0; nt < 4; nt++) bcol[nt] = bias[colblk + nt * 16 + l16];

    #pragma unroll
    for (int mt = 0; mt < 4; mt++) {
        const int sw = (quad & 1) * 16;   // 2-way bank swizzle (free)
        #pragma unroll
        for (int nt = 0; nt < 4; nt++)
            #pragma unroll
            for (int r = 0; r < 4; r++)
                ep[(quad * 4 + r) * 64 + ((nt * 16 + l16) ^ sw)] = acc[mt][nt][r] + bcol[nt];
        __syncthreads();
        #pragma unroll
        for (int p = 0; p < 4; p++) {
            int rr  = p * 4 + (lane >> 4);
            int cc  = (lane & 15) * 4;
            f32x4 vals = *(const f32x4*)&ep[rr * 64 + (cc ^ ((p & 1) * 16))];
            long row = m0 + wm + mt * 16 + rr;
            int  col = colblk + cc;
            if (colblk < 512) {
                *(f32x4*)(qout + row * 512 + col) = vals;
            } else if (colblk < 1024) {
                *(f32x4*)(kout + row * 512 + (col - 512)) = vals;
            } else {
                union { __hip_bfloat16 h[4]; short4 s4; } u;
                u.h[0] = __float2bfloat16(vals[0]); u.h[1] = __float2bfloat16(vals[1]);
                u.h[2] = __float2bfloat16(vals[2]); u.h[3] = __float2bfloat16(vals[3]);
                *(short4*)(vout + row * 512 + (col - 1024)) = u.s4;
            }
        }
        if (mt < 3) __syncthreads();  // region reused next mt (cross-wave regions disjoint, but keep counts aligned)
    }
}

// ---------------- attention ----------------

__global__ __launch_bounds__(256) void scores_kernel(
    const float* __restrict__ q, const float* __restrict__ k, float* __restrict__ sc)
{
    __shared__ float ql[512];
    int b = blockIdx.x, tid = threadIdx.x;
    const float* qrow = q + (long)(b * S_ + S_ - 1) * 512;
    ql[tid]       = qrow[tid];
    ql[tid + 256] = qrow[tid + 256];
    __syncthreads();
    int wave = tid >> 6, lane = tid & 63;
    int s0 = blockIdx.y * 64;
    float4 q1 = *(const float4*)&ql[lane * 8];
    float4 q2 = *(const float4*)&ql[lane * 8 + 4];
    for (int s = s0 + wave; s < s0 + 64; s += 4) {
        const float4* kr = (const float4*)(k + ((long)b * S_ + s) * 512);
        float4 x1 = kr[lane * 2], x2 = kr[lane * 2 + 1];
        float acc = x1.x * q1.x + x1.y * q1.y + x1.z * q1.z + x1.w * q1.w
                  + x2.x * q2.x + x2.y * q2.y + x2.z * q2.z + x2.w * q2.w;
        #pragma unroll
        for (int off = 32; off; off >>= 1) acc += __shfl_xor(acc, off);
        if (lane == 0) sc[(long)b * S_ + s] = acc;
    }
}

__global__ __launch_bounds__(256) void softmax_kernel(const float* __restrict__ sc,
                                                      float* __restrict__ attn)
{
    int b = blockIdx.x, tid = threadIdx.x;
    __shared__ float red[256];
    const float* row = sc + (long)b * S_;
    float mx = -1e30f;
    for (int s = tid; s < S_; s += 256) mx = fmaxf(mx, row[s]);
    red[tid] = mx; __syncthreads();
    for (int o = 128; o; o >>= 1) { if (tid < o) red[tid] = fmaxf(red[tid], red[tid + o]); __syncthreads(); }
    mx = red[0]; __syncthreads();
    float sum = 0.f;
    float* arow = attn + (long)b * S_;
    for (int s = tid; s < S_; s += 256) { float e = __expf(row[s] - mx); arow[s] = e; sum += e; }
    red[tid] = sum; __syncthreads();
    for (int o = 128; o; o >>= 1) { if (tid < o) red[tid] += red[tid + o]; __syncthreads(); }
    float inv = 1.0f / red[0];
    for (int s = tid; s < S_; s += 256) arow[s] *= inv;
}

__global__ __launch_bounds__(256) void h_init_kernel(const float* __restrict__ x,
                                                     float* __restrict__ h) {
    int i = blockIdx.x * 256 + threadIdx.x;  // [0, 16*512)
    int b = i >> 9, d = i & 511;
    h[i] = x[(long)(b * S_ + S_ - 1) * 512 + d];
}

__global__ __launch_bounds__(256) void sa_kernel(const __hip_bfloat16* __restrict__ v,
                                                 const float* __restrict__ attn,
                                                 float* __restrict__ h)
{
    int b  = blockIdx.x;
    int d0 = blockIdx.y * 128;
    int s0 = blockIdx.z * 512;
    int tid = threadIdx.x;
    int dt = (tid & 63) * 2;
    int sg = tid >> 6;
    float a0 = 0.f, a1 = 0.f;
    for (int s = s0 + sg; s < s0 + 512; s += 4) {
        float w = attn[(long)b * S_ + s];
        __hip_bfloat162 vv = *(const __hip_bfloat162*)(v + ((long)(b * S_ + s)) * 512 + d0 + dt);
        float2 vf = __bfloat1622float2(vv);
        a0 += w * vf.x; a1 += w * vf.y;
    }
    atomicAdd(&h[b * 512 + d0 + dt],     a0);
    atomicAdd(&h[b * 512 + d0 + dt + 1], a1);
}

// ---------------- MLP (k-split, 512 blocks) ----------------

__global__ __launch_bounds__(256) void mlp1_kernel(const float* __restrict__ h,
    const float* __restrict__ W1, const float* __restrict__ b1, float* __restrict__ h1)
{
    int b = blockIdx.x, j0 = blockIdx.y * 64;   // grid (16,32)
    __shared__ float hs[512];
    __shared__ float red[256];
    int tid = threadIdx.x;
    hs[tid]       = h[b * 512 + tid];
    hs[tid + 256] = h[b * 512 + tid + 256];
    __syncthreads();
    int jj = tid & 63, kg = tid >> 6;
    int j = j0 + jj;
    float acc = 0.f;
    for (int k2 = kg; k2 < 512; k2 += 4) acc += hs[k2] * W1[(long)k2 * M_ + j];
    red[tid] = acc; __syncthreads();
    if (kg == 0) {
        float s = red[jj] + red[64 + jj] + red[128 + jj] + red[192 + jj] + b1[j];
        h1[(long)b * M_ + j] = fmaxf(s, 0.f);
    }
}

__global__ __launch_bounds__(256) void mlp2_kernel(const float* __restrict__ h1,
    const float* __restrict__ W2, const float* __restrict__ b2, float* __restrict__ h2)
{
    int b = blockIdx.x, j0 = blockIdx.y * 64;   // grid (16,32)
    __shared__ float hs[2048];
    __shared__ float red[256];
    int tid = threadIdx.x;
    for (int t = tid; t < 2048; t += 256) hs[t] = h1[(long)b * M_ + t];
    __syncthreads();
    int jj = tid & 63, kg = tid >> 6;
    int j = j0 + jj;
    float acc = 0.f;
    for (int k2 = kg; k2 < 2048; k2 += 4) acc += hs[k2] * W2[(long)k2 * M_ + j];
    red[tid] = acc; __syncthreads();
    if (kg == 0) {
        float s = red[jj] + red[64 + jj] + red[128 + jj] + red[192 + jj] + b2[j];
        h2[(long)b * M_ + j] = fmaxf(s, 0.f);
    }
}

__global__ __launch_bounds__(256) void mlp3_kernel(const float* __restrict__ h2,
    const float* __restrict__ W3, const float* __restrict__ b3, float* __restrict__ out)
{
    int b = blockIdx.x, tid = threadIdx.x;
    __shared__ float red[256];
    float acc = 0.f;
    for (int k2 = tid; k2 < 2048; k2 += 256) acc += h2[(long)b * M_ + k2] * W3[k2];
    red[tid] = acc; __syncthreads();
    for (int o = 128; o; o >>= 1) { if (tid < o) red[tid] += red[tid + o]; __syncthreads(); }
    if (tid == 0) out[b] = red[0] + b3[0];
}

// ---------------- launch ----------------

extern "C" void kernel_launch(void* const* d_in, const int* in_sizes, int n_in,
                              void* d_out, int out_size, void* d_ws, size_t ws_size,
                              hipStream_t stream)
{
    const float* x    = (const float*)d_in[0];
    const float* Wqkv = (const float*)d_in[1];
    const float* bqkv = (const float*)d_in[2];
    const float* W1   = (const float*)d_in[3];
    const float* b1   = (const float*)d_in[4];
    const float* W2   = (const float*)d_in[5];
    const float* b2   = (const float*)d_in[6];
    const float* W3   = (const float*)d_in[7];
    const float* b3   = (const float*)d_in[8];

    float* out  = (float*)d_out;
    float* qout = out + 16;
    float* kout = qout + (size_t)ROWS * 512;

    char* ws = (char*)d_ws;
    size_t off = 0;
    auto alloc = [&](size_t bytes) -> char* {
        char* p = ws + off; off += (bytes + 255) & ~(size_t)255; return p;
    };
    __hip_bfloat16* Xb = (__hip_bfloat16*)alloc((size_t)ROWS * 512 * 2);
    __hip_bfloat16* Wt = (__hip_bfloat16*)alloc((size_t)N3D * 512 * 2);
    __hip_bfloat16* Vb = (__hip_bfloat16*)alloc((size_t)ROWS * 512 * 2);
    float* sc   = (float*)alloc((size_t)B_ * S_ * 4);
    float* attn = (float*)alloc((size_t)B_ * S_ * 4);
    float* h    = (float*)alloc((size_t)B_ * 512 * 4);
    float* h1   = (float*)alloc((size_t)B_ * M_ * 4);
    float* h2   = (float*)alloc((size_t)B_ * M_ * 4);

    hipLaunchKernelGGL(cvt_x_kernel,   dim3(ROWS * 512 / 8 / 256), dim3(256), 0, stream, x, Xb);
    hipLaunchKernelGGL(cvt_w_kernel,   dim3(N3D / 64, 512 / 64),   dim3(256), 0, stream, Wqkv, Wt);
    hipLaunchKernelGGL(gemm_qkv_kernel, dim3(N3D / 128, ROWS / 128), dim3(256), 0, stream,
                       Xb, Wt, bqkv, qout, kout, Vb);
    hipLaunchKernelGGL(scores_kernel,  dim3(B_, 64), dim3(256), 0, stream, qout, kout, sc);
    hipLaunchKernelGGL(softmax_kernel, dim3(B_),     dim3(256), 0, stream, sc, attn);
    hipLaunchKernelGGL(h_init_kernel,  dim3(B_ * 512 / 256), dim3(256), 0, stream, x, h);
    hipLaunchKernelGGL(sa_kernel,      dim3(B_, 4, 8), dim3(256), 0, stream, Vb, attn, h);
    hipLaunchKernelGGL(mlp1_kernel,    dim3(B_, 32), dim3(256), 0, stream, h, W1, b1, h1);
    hipLaunchKernelGGL(mlp2_kernel,    dim3(B_, 32), dim3(256), 0, stream, h1, W2, b2, h2);
    hipLaunchKernelGGL(mlp3_kernel,    dim3(B_),     dim3(256), 0, stream, h2, W3, b3, out);
}